// Round 2
// baseline (589.775 us; speedup 1.0000x reference)
//
#include <hip/hip_runtime.h>

// LogicGatedSNN: fused single-pass kernel, wave-per-row structure.
//   IN_FEATURES = OUT_FEATURES = 8192, THRESHOLD = 50.0
//
// v2.1: same as v2 but uses a clang ext_vector_type float4 (vfloat4) so
// __builtin_nontemporal_store accepts it (HIP_vector_type float4 is a
// class and is rejected by the builtin).
//
// Structure:
//  - One 64-lane wave owns one full row (block of 256 handles 4 rows).
//    Reduction is a pure register __shfl_xor butterfly: NO LDS, NO
//    __syncthreads (removes the barrier pair that serialized the two
//    memory bursts; counters showed 36% HBM, 7% VALU = latency-bound).
//  - Every lane computes spike itself (butterfly leaves full sum in all
//    lanes) -> no LDS broadcast.
//  - x re-read from L2 in the trace phase (32 KB, LLC-resident).
//  - Nontemporal stores for out_trace (write-only stream): avoid
//    write-allocate pollution of L2/Infinity Cache.

#define IN_F 8192
#define OUT_F 8192
#define SYN_THRESH 50.0f

typedef float vfloat4 __attribute__((ext_vector_type(4)));

__global__ __launch_bounds__(256) void snn_fused_wave(
    const float* __restrict__ x,      // [IN_F] spike_input (0/1)
    const float* __restrict__ syn,    // [OUT_F, IN_F] synapse_states
    const float* __restrict__ mp,     // [OUT_F] membrane_potential
    const float* __restrict__ thr,    // [OUT_F] adaptive_threshold
    const float* __restrict__ trace,  // [OUT_F, IN_F] eligibility_trace
    float* __restrict__ out_spikes,   // [OUT_F]
    float* __restrict__ out_vnew,     // [OUT_F]
    float* __restrict__ out_trace)    // [OUT_F, IN_F]
{
    const int wave = threadIdx.x >> 6;
    const int lane = threadIdx.x & 63;
    const int row  = (blockIdx.x << 2) | wave;   // 4 rows per block
    const long long base = (long long)row * IN_F;

    const vfloat4* __restrict__ x4   = (const vfloat4*)x;
    const vfloat4* __restrict__ syn4 = (const vfloat4*)(syn + base);
    const vfloat4* __restrict__ tr4  = (const vfloat4*)(trace + base);
    vfloat4* __restrict__ ot4        = (vfloat4*)(out_trace + base);

    // Phase 1: current = sum_i x[i] * (syn[row,i] > 50)
    // 8192 floats / 4 = 2048 vfloat4 per row; 64 lanes -> 32 vfloat4/lane.
    float sum = 0.0f;
#pragma unroll
    for (int j = 0; j < 32; ++j) {
        const int idx = (j << 6) | lane;         // lane-contiguous, coalesced
        const vfloat4 s  = syn4[idx];
        const vfloat4 xx = x4[idx];              // L2/LLC-resident (32 KB)
        sum += ((s.x > SYN_THRESH) ? xx.x : 0.0f)
             + ((s.y > SYN_THRESH) ? xx.y : 0.0f)
             + ((s.z > SYN_THRESH) ? xx.z : 0.0f)
             + ((s.w > SYN_THRESH) ? xx.w : 0.0f);
    }

    // In-register butterfly: all 64 lanes end with the full row sum.
#pragma unroll
    for (int off = 32; off > 0; off >>= 1)
        sum += __shfl_xor(sum, off, 64);

    // Phase 2: LIF update — computed redundantly by every lane (uniform).
    const float v     = mp[row] * 0.6f + sum;
    const float spike = (v >= thr[row]) ? 1.0f : 0.0f;
    if (lane == 0) {
        out_spikes[row] = spike;
        out_vnew[row]   = v * (1.0f - spike) * 0.3f;
    }

    // Phase 3: trace_new = clip(trace*0.7 + spike*x, 0, 3), streamed.
    // No barrier above -> loads can overlap the reduction latency.
    // Stores are nontemporal (never re-read).
#pragma unroll
    for (int j = 0; j < 32; ++j) {
        const int idx = (j << 6) | lane;
        vfloat4 t        = tr4[idx];
        const vfloat4 xx = x4[idx];
        t.x = fminf(fmaxf(fmaf(t.x, 0.7f, spike * xx.x), 0.0f), 3.0f);
        t.y = fminf(fmaxf(fmaf(t.y, 0.7f, spike * xx.y), 0.0f), 3.0f);
        t.z = fminf(fmaxf(fmaf(t.z, 0.7f, spike * xx.z), 0.0f), 3.0f);
        t.w = fminf(fmaxf(fmaf(t.w, 0.7f, spike * xx.w), 0.0f), 3.0f);
        __builtin_nontemporal_store(t, &ot4[idx]);
    }
}

extern "C" void kernel_launch(void* const* d_in, const int* in_sizes, int n_in,
                              void* d_out, int out_size, void* d_ws, size_t ws_size,
                              hipStream_t stream) {
    const float* x     = (const float*)d_in[0];  // spike_input        [1, 8192]
    const float* syn   = (const float*)d_in[1];  // synapse_states     [8192, 8192]
    const float* mp    = (const float*)d_in[2];  // membrane_potential [8192]
    const float* thr   = (const float*)d_in[3];  // adaptive_threshold [8192]
    const float* trace = (const float*)d_in[4];  // eligibility_trace  [8192, 8192]

    float* out = (float*)d_out;
    float* out_spikes = out;                     // [8192]
    float* out_vnew   = out + OUT_F;             // [8192]
    float* out_trace  = out + 2 * OUT_F;         // [8192, 8192]

    snn_fused_wave<<<OUT_F / 4, 256, 0, stream>>>(
        x, syn, mp, thr, trace, out_spikes, out_vnew, out_trace);
}

// Round 3
// 589.517 us; speedup vs baseline: 1.0004x; 1.0004x over previous
//
#include <hip/hip_runtime.h>

// LogicGatedSNN: fused single-pass kernel, wave-per-row, register-bounded.
//   IN_FEATURES = OUT_FEATURES = 8192, THRESHOLD = 50.0
//
// v3: v2 structure (wave-per-row, no LDS, no barriers, butterfly reduce,
// nontemporal trace stores) with the VGPR cliff fixed:
//  - __launch_bounds__(256, 8): 8 waves/EU -> compiler targets <=64 VGPR
//    -> 32 waves/CU resident (v2 hit 92 VGPR -> 16/CU -> 20% occupancy).
//  - Chunked loops (#pragma unroll 1 outer, 4 float4 inner): only ~8 vmem
//    loads (~32 data VGPRs) in flight per wave; cross-chunk latency is
//    hidden by TLP (32 waves/CU), not registers.

#define IN_F 8192
#define OUT_F 8192
#define SYN_THRESH 50.0f

typedef float vfloat4 __attribute__((ext_vector_type(4)));

__global__ __launch_bounds__(256, 8) void snn_fused_wave(
    const float* __restrict__ x,      // [IN_F] spike_input (0/1)
    const float* __restrict__ syn,    // [OUT_F, IN_F] synapse_states
    const float* __restrict__ mp,     // [OUT_F] membrane_potential
    const float* __restrict__ thr,    // [OUT_F] adaptive_threshold
    const float* __restrict__ trace,  // [OUT_F, IN_F] eligibility_trace
    float* __restrict__ out_spikes,   // [OUT_F]
    float* __restrict__ out_vnew,     // [OUT_F]
    float* __restrict__ out_trace)    // [OUT_F, IN_F]
{
    const int wave = threadIdx.x >> 6;
    const int lane = threadIdx.x & 63;
    const int row  = (blockIdx.x << 2) | wave;   // 4 rows per block
    const long long base = (long long)row * IN_F;

    const vfloat4* __restrict__ x4   = (const vfloat4*)x;
    const vfloat4* __restrict__ syn4 = (const vfloat4*)(syn + base);
    const vfloat4* __restrict__ tr4  = (const vfloat4*)(trace + base);
    vfloat4* __restrict__ ot4        = (vfloat4*)(out_trace + base);

    // Phase 1: current = sum_i x[i] * (syn[row,i] > 50)
    // 2048 vfloat4 per row / 64 lanes = 32 vfloat4 per lane,
    // processed in 8 chunks of 4 to bound live registers.
    float sum = 0.0f;
#pragma unroll 1
    for (int c = 0; c < 8; ++c) {
        vfloat4 s[4], xx[4];
#pragma unroll
        for (int u = 0; u < 4; ++u) {
            const int idx = (((c << 2) + u) << 6) | lane;  // coalesced
            s[u]  = syn4[idx];
            xx[u] = x4[idx];                 // 32 KB vector, L2-resident
        }
#pragma unroll
        for (int u = 0; u < 4; ++u) {
            sum += ((s[u].x > SYN_THRESH) ? xx[u].x : 0.0f)
                 + ((s[u].y > SYN_THRESH) ? xx[u].y : 0.0f)
                 + ((s[u].z > SYN_THRESH) ? xx[u].z : 0.0f)
                 + ((s[u].w > SYN_THRESH) ? xx[u].w : 0.0f);
        }
    }

    // In-register butterfly: all 64 lanes end with the full row sum.
#pragma unroll
    for (int off = 32; off > 0; off >>= 1)
        sum += __shfl_xor(sum, off, 64);

    // Phase 2: LIF update — uniform across the wave, every lane computes it.
    const float v     = mp[row] * 0.6f + sum;
    const float spike = (v >= thr[row]) ? 1.0f : 0.0f;
    if (lane == 0) {
        out_spikes[row] = spike;
        out_vnew[row]   = v * (1.0f - spike) * 0.3f;
    }

    // Phase 3: trace_new = clip(trace*0.7 + spike*x, 0, 3), streamed in
    // chunks of 4; stores nontemporal (never re-read -> no LLC pollution).
#pragma unroll 1
    for (int c = 0; c < 8; ++c) {
        vfloat4 t[4], xx[4];
#pragma unroll
        for (int u = 0; u < 4; ++u) {
            const int idx = (((c << 2) + u) << 6) | lane;
            t[u]  = tr4[idx];
            xx[u] = x4[idx];
        }
#pragma unroll
        for (int u = 0; u < 4; ++u) {
            const int idx = (((c << 2) + u) << 6) | lane;
            vfloat4 o;
            o.x = fminf(fmaxf(fmaf(t[u].x, 0.7f, spike * xx[u].x), 0.0f), 3.0f);
            o.y = fminf(fmaxf(fmaf(t[u].y, 0.7f, spike * xx[u].y), 0.0f), 3.0f);
            o.z = fminf(fmaxf(fmaf(t[u].z, 0.7f, spike * xx[u].z), 0.0f), 3.0f);
            o.w = fminf(fmaxf(fmaf(t[u].w, 0.7f, spike * xx[u].w), 0.0f), 3.0f);
            __builtin_nontemporal_store(o, &ot4[idx]);
        }
    }
}

extern "C" void kernel_launch(void* const* d_in, const int* in_sizes, int n_in,
                              void* d_out, int out_size, void* d_ws, size_t ws_size,
                              hipStream_t stream) {
    const float* x     = (const float*)d_in[0];  // spike_input        [1, 8192]
    const float* syn   = (const float*)d_in[1];  // synapse_states     [8192, 8192]
    const float* mp    = (const float*)d_in[2];  // membrane_potential [8192]
    const float* thr   = (const float*)d_in[3];  // adaptive_threshold [8192]
    const float* trace = (const float*)d_in[4];  // eligibility_trace  [8192, 8192]

    float* out = (float*)d_out;
    float* out_spikes = out;                     // [8192]
    float* out_vnew   = out + OUT_F;             // [8192]
    float* out_trace  = out + 2 * OUT_F;         // [8192, 8192]

    snn_fused_wave<<<OUT_F / 4, 256, 0, stream>>>(
        x, syn, mp, thr, trace, out_spikes, out_vnew, out_trace);
}